// Round 5
// baseline (3350.285 us; speedup 1.0000x reference)
//
#include <hip/hip_runtime.h>
#include <hip/hip_fp16.h>

typedef __attribute__((ext_vector_type(8))) _Float16 half8;
typedef __attribute__((ext_vector_type(4))) float float4v;

#define NPIX 16384   // 128*128
#define PITCH 130    // padded image pitch (1-px zero border)
#define NBLK 256u    // encoder grid size

// pack ranges (element index)
#define E0 1179648   // rb conv weights -> pwc
#define E1 1216512   // + tail conv
#define E2 1363968   // + pw0
#define E3 1564672   // + pwm
#define E4 1564928   // + b0p
#define E5 1664000   // + border zeroing of 3 padded buffers

// ---------------- manual grid barrier (256 blocks, all trivially co-resident) ----------------
// sense-versioned: last arriver resets cnt THEN releases gen (happens-before chain
// prevents lost counts). agent-scope acq/rel + __threadfence for cross-XCD visibility.
__device__ __forceinline__ void grid_barrier(unsigned* cnt, unsigned* gen) {
    __syncthreads();
    if (threadIdx.x == 0) {
        __threadfence();   // release this block's data (device scope)
        unsigned g = __hip_atomic_load(gen, __ATOMIC_RELAXED, __HIP_MEMORY_SCOPE_AGENT);
        unsigned old = __hip_atomic_fetch_add(cnt, 1u, __ATOMIC_ACQ_REL,
                                              __HIP_MEMORY_SCOPE_AGENT);
        if (old == NBLK - 1u) {
            __hip_atomic_store(cnt, 0u, __ATOMIC_RELAXED, __HIP_MEMORY_SCOPE_AGENT);
            __hip_atomic_fetch_add(gen, 1u, __ATOMIC_RELEASE, __HIP_MEMORY_SCOPE_AGENT);
        } else {
            while (__hip_atomic_load(gen, __ATOMIC_ACQUIRE,
                                     __HIP_MEMORY_SCOPE_AGENT) == g)
                __builtin_amdgcn_s_sleep(2);
        }
        __threadfence();   // acquire side
    }
    __syncthreads();
}

// ---------------- conv step: 3x3 shifted-window implicit GEMM ----------------
// wave tile: 16 px x 64 couts (nt 0..3), 18 K-chunks of 32. 1024 waves cover image.
template <bool RELU, bool RES>
__device__ __forceinline__ void conv_step(const _Float16* img, const _Float16* pw,
                                          const float* bias, const _Float16* res,
                                          _Float16* out) {
    int wave = threadIdx.x >> 6, lane = threadIdx.x & 63;
    int q = lane >> 4, r = lane & 15;
    int mt = (blockIdx.x << 2) + wave;
    int p0 = mt << 4;
    int py = p0 >> 7, px0 = p0 & 127;
    const _Float16* bm = img + ((py * PITCH) + px0 + r) * 64 + (q << 3);
    const _Float16* wb = pw + (lane << 3);
    float4v acc[4];
    #pragma unroll
    for (int nt = 0; nt < 4; ++nt) acc[nt] = (float4v){0.f, 0.f, 0.f, 0.f};

    #pragma unroll
    for (int kc = 0; kc < 18; ++kc) {
        int ij = kc >> 1;
        int dyp = ij / 3, dxp = ij % 3;
        half8 a = *(const half8*)(bm + dyp * (PITCH * 64) + dxp * 64 + ((kc & 1) << 5));
        #pragma unroll
        for (int nt = 0; nt < 4; ++nt) {
            half8 bf = *(const half8*)(wb + ((nt * 18 + kc) << 9));
            acc[nt] = __builtin_amdgcn_mfma_f32_16x16x32_f16(a, bf, acc[nt], 0, 0, 0);
        }
    }
    #pragma unroll
    for (int nt = 0; nt < 4; ++nt) {
        int n = (nt << 4) + r;
        float bv = bias[n];
        #pragma unroll
        for (int reg = 0; reg < 4; ++reg) {
            int xp = px0 + (q << 2) + reg;
            float v = acc[nt][reg] + bv;
            if (RES) v += (float)res[((py + 1) * PITCH + xp + 1) * 64 + n];
            if (RELU) v = fmaxf(v, 0.f);
            out[((py + 1) * PITCH + xp + 1) * 64 + n] = (_Float16)v;
        }
    }
}

// stage A: 576->256 "conv" producing A_pre[pixel][256] fp32
__device__ __forceinline__ void stage_a(const _Float16* img, const _Float16* pw,
                                        const float* b0p, float* apre) {
    int wave = threadIdx.x >> 6, lane = threadIdx.x & 63;
    int q = lane >> 4, r = lane & 15;
    int mt = (blockIdx.x << 2) + wave;
    int p0 = mt << 4;
    int py = p0 >> 7, px0 = p0 & 127;
    const _Float16* bm = img + ((py * PITCH) + px0 + r) * 64 + (q << 3);
    const _Float16* wb = pw + (lane << 3);
    float4v acc[16];
    #pragma unroll
    for (int nt = 0; nt < 16; ++nt) acc[nt] = (float4v){0.f, 0.f, 0.f, 0.f};

    #pragma unroll
    for (int kc = 0; kc < 18; ++kc) {
        int ij = kc >> 1;
        int dyp = ij / 3, dxp = ij % 3;
        half8 a = *(const half8*)(bm + dyp * (PITCH * 64) + dxp * 64 + ((kc & 1) << 5));
        #pragma unroll
        for (int nt = 0; nt < 16; ++nt) {
            half8 bf = *(const half8*)(wb + ((nt * 18 + kc) << 9));
            acc[nt] = __builtin_amdgcn_mfma_f32_16x16x32_f16(a, bf, acc[nt], 0, 0, 0);
        }
    }
    #pragma unroll
    for (int nt = 0; nt < 16; ++nt) {
        int n = (nt << 4) + r;
        float bv = b0p[n];
        #pragma unroll
        for (int reg = 0; reg < 4; ++reg)
            apre[(size_t)(p0 + (q << 2) + reg) * 256 + n] = acc[nt][reg] + bv;
    }
}

// ---------------- single-dispatch encoder: pack + head + 33 convs + stage-A ----------------
__global__ __launch_bounds__(256, 1)
void encoder_fused(const float* x, const float* head_w, const float* head_b,
                   const float* rb_w, const float* rb_b, const float* tail_w,
                   const float* tail_b, const float* mw0, const float* mw1,
                   const float* mw2, const float* mw3, const float* mw4,
                   const float* mb0,
                   _Float16* pwc, _Float16* pw0, _Float16* pwm, float* b0p,
                   _Float16* h0, _Float16* hbuf, _Float16* tbuf, float* apre,
                   unsigned* bar) {
    unsigned* cnt = bar;
    unsigned* gen = bar + 16;          // separate cache lines
    int gtid = blockIdx.x * 256 + threadIdx.x;

    // ---- phase 0: weight packing + border zeroing + head conv ----
    for (int idx = gtid; idx < E5; idx += 65536) {
        if (idx < E1) {                       // conv packs (rb + tail)
            const float* src = (idx < E0) ? rb_w : tail_w;
            int e = (idx < E0) ? idx : (idx - E0);
            int ci = e / 36864; e %= 36864;
            int j = e & 7, lane = (e >> 3) & 63, kcnt = e >> 9;
            int kc = kcnt % 18, nt = kcnt / 18;
            int k = kc * 32 + (lane >> 4) * 8 + j;
            int n = nt * 16 + (lane & 15);
            int ij = k >> 6, c = k & 63;
            pwc[idx] = (_Float16)src[ci * 36864 + (n * 64 + c) * 9 + ij];
        } else if (idx < E2) {                // pw0
            int e = idx - E1;
            int j = e & 7, lane = (e >> 3) & 63, kcnt = e >> 9;
            int kc = kcnt % 18, nt = kcnt / 18;
            int k = kc * 32 + (lane >> 4) * 8 + j;
            int n = nt * 16 + (lane & 15);
            int ij = k >> 6, c = k & 63;
            pw0[e] = (_Float16)mw0[(c * 9 + ij) * 256 + n];
        } else if (idx < E3) {                // pwm
            int e = idx - E2;
            if (e < 196608) {
                int l = e / 65536, e2 = e % 65536;
                int j = e2 & 7, lane = (e2 >> 3) & 63, kcnt = e2 >> 9;
                int kc = kcnt & 7, nt = kcnt >> 3;
                int k = kc * 32 + (lane >> 4) * 8 + j;
                int n = nt * 16 + (lane & 15);
                const float* w = (l == 0) ? mw1 : ((l == 1) ? mw2 : mw3);
                pwm[e] = (_Float16)w[k * 256 + n];
            } else {
                int e2 = e - 196608;
                int j = e2 & 7, lane = (e2 >> 3) & 63, kc = e2 >> 9;
                int k = kc * 32 + (lane >> 4) * 8 + j;
                int n = lane & 15;
                pwm[e] = (n < 3) ? (_Float16)mw4[k * 3 + n] : (_Float16)0.0f;
            }
        } else if (idx < E4) {                // b0p
            int tt = idx - E3;
            b0p[tt] = mb0[tt] + 0.5f * (mw0[578 * 256 + tt] + mw0[579 * 256 + tt]);
        } else {                              // zero borders
            int b = idx - E4;
            _Float16* buf = (b < 33024) ? h0 : ((b < 66048) ? hbuf : tbuf);
            int e = b % 33024;
            int pe = e >> 6, ch = e & 63;
            int idx2;
            if (pe < 130)      idx2 = pe;
            else if (pe < 260) idx2 = 129 * PITCH + (pe - 130);
            else if (pe < 388) idx2 = (1 + pe - 260) * PITCH;
            else               idx2 = (1 + pe - 388) * PITCH + 129;
            buf[idx2 * 64 + ch] = (_Float16)0.0f;
        }
    }
    for (int idx = gtid; idx < NPIX * 64; idx += 65536) {   // head conv
        int o = idx & 63, p = idx >> 6;
        int py = p >> 7, px = p & 127;
        float acc = head_b[o];
        #pragma unroll
        for (int c = 0; c < 3; ++c)
            #pragma unroll
            for (int i = 0; i < 3; ++i)
                #pragma unroll
                for (int jj = 0; jj < 3; ++jj) {
                    int y = py + i - 1, xx = px + jj - 1;
                    if (y >= 0 && y < 128 && xx >= 0 && xx < 128)
                        acc += x[c * 16384 + y * 128 + xx] * head_w[((o * 3 + c) * 3 + i) * 3 + jj];
                }
        h0[((py + 1) * PITCH + px + 1) * 64 + o] = (_Float16)acc;
    }
    grid_barrier(cnt, gen);

    // ---- 16 resblocks ----
    const _Float16* hin = h0;
    #pragma unroll 1
    for (int i = 0; i < 16; ++i) {
        conv_step<true, false>(hin, pwc + (size_t)(2 * i) * 36864, rb_b + i * 128,
                               nullptr, tbuf);
        grid_barrier(cnt, gen);
        conv_step<false, true>(tbuf, pwc + (size_t)(2 * i + 1) * 36864,
                               rb_b + i * 128 + 64, hin, hbuf);
        grid_barrier(cnt, gen);
        hin = hbuf;
    }
    // tail: feat = h0 + conv(hbuf)  -> tbuf
    conv_step<false, true>(hbuf, pwc + (size_t)32 * 36864, tail_b, h0, tbuf);
    grid_barrier(cnt, gen);
    // stage A
    stage_a(tbuf, pw0, b0p, apre);
}

// ---------------- fused LIIF MLP + ensembling ----------------
// 256 thr (4 waves) = 32 px = 128 samples. act[128][256] fp16, XOR-swizzled:
// idx = (row<<8) + (((col>>3) ^ (row&7))<<3) + (col&7)  (A-reads & u16 writes conflict-free).
// Wave w: M-half mi=w>>1 (64 rows, mt 0..3), N-half nj=w&1 (128 cols, nt 0..7).
__global__ __launch_bounds__(256, 2)
void mlp_kernel(const float* __restrict__ apre, const float* __restrict__ mw0,
                const float* __restrict__ mb1, const float* __restrict__ mb2,
                const float* __restrict__ mb3, const float* __restrict__ mb4,
                const _Float16* __restrict__ pwm, const _Float16* __restrict__ pw4,
                float* __restrict__ out) {
    __shared__ _Float16 act[128 * 256];
    __shared__ float sArea[128], sRelH[128], sRelW[128];
    __shared__ int sCell[128];

    int t = threadIdx.x;
    int p0 = blockIdx.x << 5;         // 32 pixels

    if (t < 128) {
        int lp = t >> 2, rc = t & 3;
        int p = p0 + lp;
        int oh = p >> 9, ow = p & 511;
        float sh = (oh + 0.5f) * (2.0f / 512.0f) - 1.0f;
        float sw_ = (ow + 0.5f) * (2.0f / 512.0f) - 1.0f;
        float gh = sh + (((rc >> 1) != 0) ? (1.0f / 128.0f) : (-1.0f / 128.0f));
        float gw = sw_ + (((rc & 1) != 0) ? (1.0f / 128.0f) : (-1.0f / 128.0f));
        const float lim = 1.0f - 1e-6f;
        gh = fminf(fmaxf(gh, -lim), lim);
        gw = fminf(fmaxf(gw, -lim), lim);
        int iy = (int)rintf(((gh + 1.0f) * 128.0f - 1.0f) * 0.5f);  // round-half-even
        int ix = (int)rintf(((gw + 1.0f) * 128.0f - 1.0f) * 0.5f);
        iy = iy < 0 ? 0 : (iy > 127 ? 127 : iy);
        ix = ix < 0 ? 0 : (ix > 127 ? 127 : ix);
        float cy = (iy + 0.5f) * (2.0f / 128.0f) - 1.0f;
        float cx = (ix + 0.5f) * (2.0f / 128.0f) - 1.0f;
        float rh = (sh - cy) * 128.0f;
        float rw = (sw_ - cx) * 128.0f;
        sCell[t] = (iy << 7) + ix;
        sRelH[t] = rh; sRelW[t] = rw;
        sArea[t] = fabsf(rh * rw);
    }
    __syncthreads();

    // ---- layer 1: thread t -> row t>>1, col-half t&1 ----
    {
        int s = t >> 1, half = t & 1;
        int nb0 = half << 7;
        float rh = sRelH[s], rw = sRelW[s];
        const float* ap = apre + ((size_t)sCell[s] << 8) + nb0;
        const float* wh = mw0 + 576 * 256 + nb0;
        const float* ww = mw0 + 577 * 256 + nb0;
        int swr = s & 7;
        #pragma unroll
        for (int nb = 0; nb < 128; nb += 8) {
            float4v f0 = *(const float4v*)(ap + nb);
            float4v f1 = *(const float4v*)(ap + nb + 4);
            float4v h0v = *(const float4v*)(wh + nb);
            float4v h1v = *(const float4v*)(wh + nb + 4);
            float4v w0v = *(const float4v*)(ww + nb);
            float4v w1v = *(const float4v*)(ww + nb + 4);
            half8 hv;
            #pragma unroll
            for (int k = 0; k < 4; ++k) {
                hv[k]     = (_Float16)fmaxf(f0[k] + rh * h0v[k] + rw * w0v[k], 0.f);
                hv[k + 4] = (_Float16)fmaxf(f1[k] + rh * h1v[k] + rw * w1v[k], 0.f);
            }
            int g = (nb0 + nb) >> 3;
            *(half8*)(act + (s << 8) + ((g ^ swr) << 3)) = hv;
        }
    }
    __syncthreads();

    int wave = t >> 6, lane = t & 63, q = lane >> 4, r = lane & 15;
    int mi = wave >> 1, nj = wave & 1;
    int rowbase = (mi << 6) + r;      // A rows
    int sw = r & 7;

    float4v acc[4][8];
    #pragma unroll 1
    for (int l = 0; l < 3; ++l) {
        #pragma unroll
        for (int mt = 0; mt < 4; ++mt)
            #pragma unroll
            for (int nt = 0; nt < 8; ++nt)
                acc[mt][nt] = (float4v){0.f, 0.f, 0.f, 0.f};
        const _Float16* pwl = pwm + l * 65536 + (nj << 15) + (lane << 3);
        #pragma unroll
        for (int kc = 0; kc < 8; ++kc) {
            half8 A[4];
            int cof = (((kc << 2) + q) ^ sw) << 3;
            #pragma unroll
            for (int mt = 0; mt < 4; ++mt)
                A[mt] = *(const half8*)(act + ((rowbase + (mt << 4)) << 8) + cof);
            #pragma unroll
            for (int nt = 0; nt < 8; ++nt) {
                half8 B = *(const half8*)(pwl + (nt << 12) + (kc << 9));
                #pragma unroll
                for (int mt = 0; mt < 4; ++mt)
                    acc[mt][nt] = __builtin_amdgcn_mfma_f32_16x16x32_f16(
                        A[mt], B, acc[mt][nt], 0, 0, 0);
            }
        }
        const float* mb = (l == 0) ? mb1 : ((l == 1) ? mb2 : mb3);
        float bv[8];
        #pragma unroll
        for (int nt = 0; nt < 8; ++nt)
            bv[nt] = mb[(nj << 7) + (nt << 4) + r];
        __syncthreads();   // all waves done reading act
        #pragma unroll
        for (int mt = 0; mt < 4; ++mt)
            #pragma unroll
            for (int nt = 0; nt < 8; ++nt) {
                int colg = (nj << 4) + (nt << 1) + (r >> 3);   // col>>3
                #pragma unroll
                for (int reg = 0; reg < 4; ++reg) {
                    int row = (mi << 6) + (mt << 4) + (q << 2) + reg;
                    float v = fmaxf(acc[mt][nt][reg] + bv[nt], 0.f);
                    act[(row << 8) + (((colg ^ (row & 7)) << 3)) + (r & 7)] = (_Float16)v;
                }
            }
        __syncthreads();
    }

    // ---- final layer: wave handles rows wave*32..+31 (2 m-tiles), N=16 (padded mw4) ----
    float4v af[2];
    af[0] = (float4v){0.f, 0.f, 0.f, 0.f};
    af[1] = (float4v){0.f, 0.f, 0.f, 0.f};
    #pragma unroll
    for (int kc = 0; kc < 8; ++kc) {
        half8 B = *(const half8*)(pw4 + (kc << 9) + (lane << 3));
        int cof = (((kc << 2) + q) ^ sw) << 3;
        #pragma unroll
        for (int i = 0; i < 2; ++i) {
            int row = (wave << 5) + (i << 4) + r;
            half8 A = *(const half8*)(act + (row << 8) + cof);
            af[i] = __builtin_amdgcn_mfma_f32_16x16x32_f16(A, B, af[i], 0, 0, 0);
        }
    }
    if (r < 3) {
        float b4 = mb4[r];
        #pragma unroll
        for (int i = 0; i < 2; ++i) {
            int lp = (wave << 3) + (i << 2) + q;
            float a0 = sArea[lp * 4 + 0], a1 = sArea[lp * 4 + 1];
            float a2 = sArea[lp * 4 + 2], a3 = sArea[lp * 4 + 3];
            float tot = a0 + a1 + a2 + a3 + 1e-9f;
            float num = (af[i][0] + b4) * a3 + (af[i][1] + b4) * a2
                      + (af[i][2] + b4) * a1 + (af[i][3] + b4) * a0;
            float v = num / tot;
            v = fminf(fmaxf(v, 0.0f), 1.0f);
            out[r * 262144 + p0 + lp] = v;
        }
    }
}

extern "C" void kernel_launch(void* const* d_in, const int* in_sizes, int n_in,
                              void* d_out, int out_size, void* d_ws, size_t ws_size,
                              hipStream_t stream) {
    (void)in_sizes; (void)n_in; (void)out_size; (void)ws_size;
    const float* x      = (const float*)d_in[0];
    const float* head_w = (const float*)d_in[2];
    const float* head_b = (const float*)d_in[3];
    const float* rb_w   = (const float*)d_in[4];
    const float* rb_b   = (const float*)d_in[5];
    const float* tail_w = (const float*)d_in[6];
    const float* tail_b = (const float*)d_in[7];
    const float* mw0    = (const float*)d_in[8];
    const float* mb0    = (const float*)d_in[9];
    const float* mw1    = (const float*)d_in[10];
    const float* mb1    = (const float*)d_in[11];
    const float* mw2    = (const float*)d_in[12];
    const float* mb2    = (const float*)d_in[13];
    const float* mw3    = (const float*)d_in[14];
    const float* mb3    = (const float*)d_in[15];
    const float* mw4    = (const float*)d_in[16];
    const float* mb4    = (const float*)d_in[17];
    float* out = (float*)d_out;

    const size_t PBUF = (size_t)PITCH * PITCH * 64;
    char* w = (char*)d_ws;
    auto take = [&](size_t n) { char* p = w; w += (n + 255) & ~(size_t)255; return p; };
    unsigned* bar  = (unsigned*)take(256u);               // grid-barrier state
    _Float16* pwc  = (_Float16*)take(33u * 36864u * 2u);
    _Float16* pw0  = (_Float16*)take(147456u * 2u);
    _Float16* pwm  = (_Float16*)take(200704u * 2u);
    float*    b0p  = (float*)take(256u * 4u);
    _Float16* h0   = (_Float16*)take(PBUF * 2u);
    _Float16* hbuf = (_Float16*)take(PBUF * 2u);
    _Float16* tbuf = (_Float16*)take(PBUF * 2u);          // also holds feat at the end
    float*    apre = (float*)take((size_t)NPIX * 256u * 4u);

    hipMemsetAsync(bar, 0, 256, stream);                  // zero barrier state every call

    encoder_fused<<<NBLK, 256, 0, stream>>>(
        x, head_w, head_b, rb_w, rb_b, tail_w, tail_b, mw0, mw1, mw2, mw3, mw4,
        mb0, pwc, pw0, pwm, b0p, h0, hbuf, tbuf, apre, bar);

    mlp_kernel<<<8192, 256, 0, stream>>>(apre, mw0, mb1, mb2, mb3, mb4,
                                         pwm, pwm + 196608, out);
}

// Round 6
// 1563.979 us; speedup vs baseline: 2.1422x; 2.1422x over previous
//
#include <hip/hip_runtime.h>
#include <hip/hip_fp16.h>

typedef __attribute__((ext_vector_type(8))) _Float16 half8;
typedef __attribute__((ext_vector_type(4))) _Float16 half4;
typedef __attribute__((ext_vector_type(4))) float float4v;

#define NPIX 16384   // 128*128
#define PITCH 130    // padded image pitch (1-px zero border)
#define NBLK 256u    // encoder grid size (512 thr each, 1 block/CU)

// pack ranges (element index)
#define E0 1179648   // rb conv weights -> pwc
#define E1 1216512   // + tail conv
#define E2 1363968   // + pw0
#define E3 1564672   // + pwm
#define E4 1564928   // + b0p
#define E5 1664000   // + border zeroing of 3 padded buffers

// ---------------- manual grid barrier ----------------
// RELAXED spin (no cache-op per poll!) + one agent fence each side.
// R5 lesson: agent-scope ACQUIRE in the spin loop emits buffer_inv per poll ->
// L2-invalidate storm (FETCH 93MB, 1790us). Poll relaxed; fence once.
__device__ __forceinline__ void grid_barrier(unsigned* cnt, unsigned* gen) {
    __syncthreads();
    if (threadIdx.x == 0) {
        unsigned g = __hip_atomic_load(gen, __ATOMIC_RELAXED, __HIP_MEMORY_SCOPE_AGENT);
        __threadfence();   // release: wb dirty L2 before signaling arrival
        unsigned old = __hip_atomic_fetch_add(cnt, 1u, __ATOMIC_RELAXED,
                                              __HIP_MEMORY_SCOPE_AGENT);
        if (old == NBLK - 1u) {
            __hip_atomic_store(cnt, 0u, __ATOMIC_RELAXED, __HIP_MEMORY_SCOPE_AGENT);
            __hip_atomic_fetch_add(gen, 1u, __ATOMIC_RELEASE, __HIP_MEMORY_SCOPE_AGENT);
        } else {
            while (__hip_atomic_load(gen, __ATOMIC_RELAXED,
                                     __HIP_MEMORY_SCOPE_AGENT) == g)
                __builtin_amdgcn_s_sleep(8);
        }
        __threadfence();   // acquire: one L1/L2 invalidate after release observed
    }
    __syncthreads();
}

// ---------------- conv step: 3x3 shifted-window implicit GEMM ----------------
// 512-thr block owns 64 px (half row). Wave w: pixels p_base+(w>>1)*16, cout
// half (w&1)*32 (nt = (w&1)*2+i). 2048 waves = all resident, 2/SIMD.
template <bool RELU, bool RES>
__device__ __forceinline__ void conv_step(const _Float16* img, const _Float16* pw,
                                          const float* bias, const _Float16* res,
                                          _Float16* out, int p_base) {
    int wave = threadIdx.x >> 6, lane = threadIdx.x & 63;
    int q = lane >> 4, r = lane & 15;
    int p0 = p_base + ((wave >> 1) << 4);
    int nh = wave & 1;
    int py = p0 >> 7, px0 = p0 & 127;
    const _Float16* bm = img + ((py * PITCH) + px0 + r) * 64 + (q << 3);
    const _Float16* wb = pw + (lane << 3);
    float4v acc[2];
    acc[0] = (float4v){0.f, 0.f, 0.f, 0.f};
    acc[1] = (float4v){0.f, 0.f, 0.f, 0.f};

    #pragma unroll
    for (int kc = 0; kc < 18; ++kc) {
        int ij = kc >> 1;
        int dyp = ij / 3, dxp = ij % 3;
        half8 a = *(const half8*)(bm + dyp * (PITCH * 64) + dxp * 64 + ((kc & 1) << 5));
        #pragma unroll
        for (int i = 0; i < 2; ++i) {
            int nt = (nh << 1) + i;
            half8 bf = *(const half8*)(wb + ((nt * 18 + kc) << 9));
            acc[i] = __builtin_amdgcn_mfma_f32_16x16x32_f16(a, bf, acc[i], 0, 0, 0);
        }
    }
    #pragma unroll
    for (int i = 0; i < 2; ++i) {
        int n = (((nh << 1) + i) << 4) + r;
        float bv = bias[n];
        #pragma unroll
        for (int reg = 0; reg < 4; ++reg) {
            int xp = px0 + (q << 2) + reg;
            float v = acc[i][reg] + bv;
            if (RES) v += (float)res[((py + 1) * PITCH + xp + 1) * 64 + n];
            if (RELU) v = fmaxf(v, 0.f);
            out[((py + 1) * PITCH + xp + 1) * 64 + n] = (_Float16)v;
        }
    }
}

// stage A: 576->256 "conv" -> A_pre[pixel][256] fp32. Wave w: pixels
// p_base+(w>>1)*16, cout half (w&1)*128 (8 nt tiles).
__device__ __forceinline__ void stage_a(const _Float16* img, const _Float16* pw,
                                        const float* b0p, float* apre, int p_base) {
    int wave = threadIdx.x >> 6, lane = threadIdx.x & 63;
    int q = lane >> 4, r = lane & 15;
    int p0 = p_base + ((wave >> 1) << 4);
    int nh = wave & 1;
    int py = p0 >> 7, px0 = p0 & 127;
    const _Float16* bm = img + ((py * PITCH) + px0 + r) * 64 + (q << 3);
    const _Float16* wb = pw + (lane << 3);
    float4v acc[8];
    #pragma unroll
    for (int i = 0; i < 8; ++i) acc[i] = (float4v){0.f, 0.f, 0.f, 0.f};

    #pragma unroll
    for (int kc = 0; kc < 18; ++kc) {
        int ij = kc >> 1;
        int dyp = ij / 3, dxp = ij % 3;
        half8 a = *(const half8*)(bm + dyp * (PITCH * 64) + dxp * 64 + ((kc & 1) << 5));
        #pragma unroll
        for (int i = 0; i < 8; ++i) {
            int nt = (nh << 3) + i;
            half8 bf = *(const half8*)(wb + ((nt * 18 + kc) << 9));
            acc[i] = __builtin_amdgcn_mfma_f32_16x16x32_f16(a, bf, acc[i], 0, 0, 0);
        }
    }
    #pragma unroll
    for (int i = 0; i < 8; ++i) {
        int n = (((nh << 3) + i) << 4) + r;
        float bv = b0p[n];
        #pragma unroll
        for (int reg = 0; reg < 4; ++reg)
            apre[(size_t)(p0 + (q << 2) + reg) * 256 + n] = acc[i][reg] + bv;
    }
}

// ---------------- single-dispatch encoder ----------------
// XCD-contiguous strips: block b -> pixels (b&7)*2048 + (b>>3)*64, so XCD x
// (round-robin b%8) owns rows [x*16, x*16+16); cross-XCD halo = strip edges only.
__global__ __launch_bounds__(512, 1)
void encoder_fused(const float* x, const float* head_w, const float* head_b,
                   const float* rb_w, const float* rb_b, const float* tail_w,
                   const float* tail_b, const float* mw0, const float* mw1,
                   const float* mw2, const float* mw3, const float* mw4,
                   const float* mb0,
                   _Float16* pwc, _Float16* pw0, _Float16* pwm, float* b0p,
                   _Float16* h0, _Float16* hbuf, _Float16* tbuf, float* apre,
                   unsigned* bar) {
    unsigned* cnt = bar;
    unsigned* gen = bar + 16;          // separate cache lines
    int gtid = blockIdx.x * 512 + threadIdx.x;
    int p_base = ((blockIdx.x & 7) << 11) + ((blockIdx.x >> 3) << 6);

    // ---- phase 0: weight packing + border zeroing + head conv ----
    for (int idx = gtid; idx < E5; idx += 131072) {
        if (idx < E1) {                       // conv packs (rb + tail)
            const float* src = (idx < E0) ? rb_w : tail_w;
            int e = (idx < E0) ? idx : (idx - E0);
            int ci = e / 36864; e %= 36864;
            int j = e & 7, lane = (e >> 3) & 63, kcnt = e >> 9;
            int kc = kcnt % 18, nt = kcnt / 18;
            int k = kc * 32 + (lane >> 4) * 8 + j;
            int n = nt * 16 + (lane & 15);
            int ij = k >> 6, c = k & 63;
            pwc[idx] = (_Float16)src[ci * 36864 + (n * 64 + c) * 9 + ij];
        } else if (idx < E2) {                // pw0
            int e = idx - E1;
            int j = e & 7, lane = (e >> 3) & 63, kcnt = e >> 9;
            int kc = kcnt % 18, nt = kcnt / 18;
            int k = kc * 32 + (lane >> 4) * 8 + j;
            int n = nt * 16 + (lane & 15);
            int ij = k >> 6, c = k & 63;
            pw0[e] = (_Float16)mw0[(c * 9 + ij) * 256 + n];
        } else if (idx < E3) {                // pwm
            int e = idx - E2;
            if (e < 196608) {
                int l = e / 65536, e2 = e % 65536;
                int j = e2 & 7, lane = (e2 >> 3) & 63, kcnt = e2 >> 9;
                int kc = kcnt & 7, nt = kcnt >> 3;
                int k = kc * 32 + (lane >> 4) * 8 + j;
                int n = nt * 16 + (lane & 15);
                const float* w = (l == 0) ? mw1 : ((l == 1) ? mw2 : mw3);
                pwm[e] = (_Float16)w[k * 256 + n];
            } else {
                int e2 = e - 196608;
                int j = e2 & 7, lane = (e2 >> 3) & 63, kc = e2 >> 9;
                int k = kc * 32 + (lane >> 4) * 8 + j;
                int n = lane & 15;
                pwm[e] = (n < 3) ? (_Float16)mw4[k * 3 + n] : (_Float16)0.0f;
            }
        } else if (idx < E4) {                // b0p
            int tt = idx - E3;
            b0p[tt] = mb0[tt] + 0.5f * (mw0[578 * 256 + tt] + mw0[579 * 256 + tt]);
        } else {                              // zero borders
            int b = idx - E4;
            _Float16* buf = (b < 33024) ? h0 : ((b < 66048) ? hbuf : tbuf);
            int e = b % 33024;
            int pe = e >> 6, ch = e & 63;
            int idx2;
            if (pe < 130)      idx2 = pe;
            else if (pe < 260) idx2 = 129 * PITCH + (pe - 130);
            else if (pe < 388) idx2 = (1 + pe - 260) * PITCH;
            else               idx2 = (1 + pe - 388) * PITCH + 129;
            buf[idx2 * 64 + ch] = (_Float16)0.0f;
        }
    }
    #pragma unroll 1
    for (int it = 0; it < 8; ++it) {          // head conv (block's own 64 px)
        int v = it * 512 + threadIdx.x;
        int o = v & 63, pl = v >> 6;
        int p = p_base + pl;
        int py = p >> 7, px = p & 127;
        float acc = head_b[o];
        #pragma unroll
        for (int c = 0; c < 3; ++c)
            #pragma unroll
            for (int i = 0; i < 3; ++i)
                #pragma unroll
                for (int jj = 0; jj < 3; ++jj) {
                    int y = py + i - 1, xx = px + jj - 1;
                    if (y >= 0 && y < 128 && xx >= 0 && xx < 128)
                        acc += x[c * 16384 + y * 128 + xx] * head_w[((o * 3 + c) * 3 + i) * 3 + jj];
                }
        h0[((py + 1) * PITCH + px + 1) * 64 + o] = (_Float16)acc;
    }
    grid_barrier(cnt, gen);

    // ---- 16 resblocks ----
    const _Float16* hin = h0;
    #pragma unroll 1
    for (int i = 0; i < 16; ++i) {
        conv_step<true, false>(hin, pwc + (size_t)(2 * i) * 36864, rb_b + i * 128,
                               nullptr, tbuf, p_base);
        grid_barrier(cnt, gen);
        conv_step<false, true>(tbuf, pwc + (size_t)(2 * i + 1) * 36864,
                               rb_b + i * 128 + 64, hin, hbuf, p_base);
        grid_barrier(cnt, gen);
        hin = hbuf;
    }
    // tail: feat = h0 + conv(hbuf)  -> tbuf
    conv_step<false, true>(hbuf, pwc + (size_t)32 * 36864, tail_b, h0, tbuf, p_base);
    grid_barrier(cnt, gen);
    // stage A
    stage_a(tbuf, pw0, b0p, apre, p_base);
}

// ---------------- fused LIIF MLP + ensembling (R1 version, measured 446us) ----------------
// Block: 256 thr (4 waves) = 16 output pixels = 64 samples (s = lp*4 + rc).
// act in LDS [64][264] fp16; 3 hidden 256x256 fp16-MFMA layers; final 256->3 (N padded to 16).
__global__ __launch_bounds__(256, 3)
void mlp_kernel(const float* __restrict__ apre, const float* __restrict__ mw0,
                const float* __restrict__ mb1, const float* __restrict__ mb2,
                const float* __restrict__ mb3, const float* __restrict__ mb4,
                const _Float16* __restrict__ pwm, const _Float16* __restrict__ pw4,
                float* __restrict__ out) {
    __shared__ _Float16 act[64 * 264];
    __shared__ float sArea[64], sRelH[64], sRelW[64];
    __shared__ int sCell[64];
    __shared__ float sWh[256], sWw[256];

    int t = threadIdx.x;
    int p0 = blockIdx.x << 4;

    if (t < 64) {
        int lp = t >> 2, rc = t & 3;
        int p = p0 + lp;
        int oh = p >> 9, ow = p & 511;
        float sh = (oh + 0.5f) * (2.0f / 512.0f) - 1.0f;
        float sw = (ow + 0.5f) * (2.0f / 512.0f) - 1.0f;
        float gh = sh + (((rc >> 1) != 0) ? (1.0f / 128.0f) : (-1.0f / 128.0f));
        float gw = sw + (((rc & 1) != 0) ? (1.0f / 128.0f) : (-1.0f / 128.0f));
        const float lim = 1.0f - 1e-6f;
        gh = fminf(fmaxf(gh, -lim), lim);
        gw = fminf(fmaxf(gw, -lim), lim);
        int iy = (int)rintf(((gh + 1.0f) * 128.0f - 1.0f) * 0.5f);  // round-half-even
        int ix = (int)rintf(((gw + 1.0f) * 128.0f - 1.0f) * 0.5f);
        iy = iy < 0 ? 0 : (iy > 127 ? 127 : iy);
        ix = ix < 0 ? 0 : (ix > 127 ? 127 : ix);
        float cy = (iy + 0.5f) * (2.0f / 128.0f) - 1.0f;
        float cx = (ix + 0.5f) * (2.0f / 128.0f) - 1.0f;
        float rh = (sh - cy) * 128.0f;
        float rw = (sw - cx) * 128.0f;
        sCell[t] = (iy << 7) + ix;
        sRelH[t] = rh; sRelW[t] = rw;
        sArea[t] = fabsf(rh * rw);
    }
    sWh[t] = mw0[576 * 256 + t];
    sWw[t] = mw0[577 * 256 + t];
    __syncthreads();

    // layer 1: t1 = relu(A_pre[cell] + rel_h*W0[576] + rel_w*W0[577])
    {
        int s = t >> 2, nb = (t & 3) << 6;
        float rh = sRelH[s], rw = sRelW[s];
        const float* ap = apre + ((size_t)sCell[s] << 8) + nb;
        _Float16* dst = act + s * 264 + nb;
        #pragma unroll
        for (int n = 0; n < 64; n += 4) {
            float4v ld = *(const float4v*)(ap + n);
            half4 hv;
            #pragma unroll
            for (int kk = 0; kk < 4; ++kk) {
                float v = ld[kk] + rh * sWh[nb + n + kk] + rw * sWw[nb + n + kk];
                hv[kk] = (_Float16)fmaxf(v, 0.0f);
            }
            *(half4*)(dst + n) = hv;
        }
    }
    __syncthreads();

    int wave = t >> 6, lane = t & 63, q = lane >> 4, r = lane & 15;

    // hidden layers: each wave does all 64 rows x its 64-col quarter (4x4 frag tiles)
    float4v acc[4][4];
    #pragma unroll 1
    for (int l = 0; l < 3; ++l) {
        #pragma unroll
        for (int mt = 0; mt < 4; ++mt)
            #pragma unroll
            for (int nt = 0; nt < 4; ++nt)
                acc[mt][nt] = (float4v){0.f, 0.f, 0.f, 0.f};
        const _Float16* pw = pwm + l * 65536;
        for (int kc = 0; kc < 8; ++kc) {
            half8 A[4], B[4];
            #pragma unroll
            for (int mt = 0; mt < 4; ++mt)
                A[mt] = *(const half8*)(act + (mt * 16 + r) * 264 + kc * 32 + q * 8);
            #pragma unroll
            for (int nt = 0; nt < 4; ++nt)
                B[nt] = *(const half8*)(pw + ((((wave * 4 + nt) * 8 + kc) * 64 + lane) << 3));
            #pragma unroll
            for (int mt = 0; mt < 4; ++mt)
                #pragma unroll
                for (int nt = 0; nt < 4; ++nt)
                    acc[mt][nt] = __builtin_amdgcn_mfma_f32_16x16x32_f16(
                        A[mt], B[nt], acc[mt][nt], 0, 0, 0);
        }
        const float* mb = (l == 0) ? mb1 : ((l == 1) ? mb2 : mb3);
        float bv[4];
        #pragma unroll
        for (int nt = 0; nt < 4; ++nt)
            bv[nt] = mb[(wave << 6) + nt * 16 + r];
        __syncthreads();   // all waves done reading act
        #pragma unroll
        for (int mt = 0; mt < 4; ++mt)
            #pragma unroll
            for (int nt = 0; nt < 4; ++nt)
                #pragma unroll
                for (int reg = 0; reg < 4; ++reg) {
                    float v = fmaxf(acc[mt][nt][reg] + bv[nt], 0.0f);
                    act[(mt * 16 + q * 4 + reg) * 264 + (wave << 6) + nt * 16 + r] = (_Float16)v;
                }
        __syncthreads();
    }

    // final layer: wave handles rows 16w..16w+15; D rows = 4 samples of pixel (wave*4+q)
    float4v af = {0.f, 0.f, 0.f, 0.f};
    #pragma unroll
    for (int kc = 0; kc < 8; ++kc) {
        half8 A = *(const half8*)(act + (wave * 16 + r) * 264 + kc * 32 + q * 8);
        half8 B = *(const half8*)(pw4 + ((kc * 64 + lane) << 3));
        af = __builtin_amdgcn_mfma_f32_16x16x32_f16(A, B, af, 0, 0, 0);
    }
    if (r < 3) {   // reg rc holds pred[pixel=wave*4+q][rc][ch=r]
        float b4 = mb4[r];
        int lp = (wave << 2) + q;
        float a0 = sArea[lp * 4 + 0], a1 = sArea[lp * 4 + 1];
        float a2 = sArea[lp * 4 + 2], a3 = sArea[lp * 4 + 3];
        float tot = a0 + a1 + a2 + a3 + 1e-9f;
        float num = (af[0] + b4) * a3 + (af[1] + b4) * a2
                  + (af[2] + b4) * a1 + (af[3] + b4) * a0;
        float v = num / tot;
        v = fminf(fmaxf(v, 0.0f), 1.0f);
        out[r * 262144 + p0 + lp] = v;
    }
}

extern "C" void kernel_launch(void* const* d_in, const int* in_sizes, int n_in,
                              void* d_out, int out_size, void* d_ws, size_t ws_size,
                              hipStream_t stream) {
    (void)in_sizes; (void)n_in; (void)out_size; (void)ws_size;
    const float* x      = (const float*)d_in[0];
    const float* head_w = (const float*)d_in[2];
    const float* head_b = (const float*)d_in[3];
    const float* rb_w   = (const float*)d_in[4];
    const float* rb_b   = (const float*)d_in[5];
    const float* tail_w = (const float*)d_in[6];
    const float* tail_b = (const float*)d_in[7];
    const float* mw0    = (const float*)d_in[8];
    const float* mb0    = (const float*)d_in[9];
    const float* mw1    = (const float*)d_in[10];
    const float* mb1    = (const float*)d_in[11];
    const float* mw2    = (const float*)d_in[12];
    const float* mb2    = (const float*)d_in[13];
    const float* mw3    = (const float*)d_in[14];
    const float* mb3    = (const float*)d_in[15];
    const float* mw4    = (const float*)d_in[16];
    const float* mb4    = (const float*)d_in[17];
    float* out = (float*)d_out;

    const size_t PBUF = (size_t)PITCH * PITCH * 64;
    char* w = (char*)d_ws;
    auto take = [&](size_t n) { char* p = w; w += (n + 255) & ~(size_t)255; return p; };
    unsigned* bar  = (unsigned*)take(256u);               // grid-barrier state
    _Float16* pwc  = (_Float16*)take(33u * 36864u * 2u);
    _Float16* pw0  = (_Float16*)take(147456u * 2u);
    _Float16* pwm  = (_Float16*)take(200704u * 2u);
    float*    b0p  = (float*)take(256u * 4u);
    _Float16* h0   = (_Float16*)take(PBUF * 2u);
    _Float16* hbuf = (_Float16*)take(PBUF * 2u);
    _Float16* tbuf = (_Float16*)take(PBUF * 2u);          // also holds feat at the end
    float*    apre = (float*)take((size_t)NPIX * 256u * 4u);

    hipMemsetAsync(bar, 0, 256, stream);                  // zero barrier state every call

    encoder_fused<<<NBLK, 512, 0, stream>>>(
        x, head_w, head_b, rb_w, rb_b, tail_w, tail_b, mw0, mw1, mw2, mw3, mw4,
        mb0, pwc, pw0, pwm, b0p, h0, hbuf, tbuf, apre, bar);

    mlp_kernel<<<16384, 256, 0, stream>>>(apre, mw0, mb1, mb2, mb3, mb4,
                                          pwm, pwm + 196608, out);
}